// Round 1
// 1157.600 us; speedup vs baseline: 1.0701x; 1.0701x over previous
//
#include <hip/hip_runtime.h>

#define NPAPER 200000
#define NMESH  30000
#define NNODES 230000
#define ETRAIN 2000000
#define EPOS   500000
#define ENEG   500000

typedef _Float16 f16;
typedef __attribute__((ext_vector_type(8))) _Float16 f16x8;
typedef __attribute__((ext_vector_type(4))) _Float16 f16x4;

__device__ __forceinline__ void fma4(float4& a, float s, const float4 w) {
    a.x = fmaf(s, w.x, a.x);
    a.y = fmaf(s, w.y, a.y);
    a.z = fmaf(s, w.z, a.z);
    a.w = fmaf(s, w.w, a.w);
}

// ---------------- encode: out[row][0:16] = x[row][:] @ W + b ----------------
template <int D>
__global__ __launch_bounds__(256) void encode_kernel(
    const float* __restrict__ x, const float* __restrict__ w,
    const float* __restrict__ bias, float* __restrict__ out, int nrows) {
    constexpr int KP = 16;
    __shared__ float wlds[D * 16];       // [k][16]
    __shared__ float xlds[256 * 20];     // [row][KP] stride 20 floats
    __shared__ float blds[16];

    for (int i = threadIdx.x; i < D * 4; i += 256)
        reinterpret_cast<float4*>(wlds)[i] =
            reinterpret_cast<const float4*>(w)[i];
    if (threadIdx.x < 16) blds[threadIdx.x] = bias[threadIdx.x];

    const int g = threadIdx.x & 3;
    const int rg = threadIdx.x >> 2;  // 0..63
    const int row0 = blockIdx.x * 256;

    float4 acc[4];
#pragma unroll
    for (int j = 0; j < 4; j++) acc[j] = make_float4(0.f, 0.f, 0.f, 0.f);

    for (int p = 0; p < D / KP; p++) {
        __syncthreads();
        for (int i = threadIdx.x; i < 1024; i += 256) {
            const int rr = i >> 2, q = i & 3;
            const int grow = min(row0 + rr, nrows - 1);
            *reinterpret_cast<float4*>(xlds + rr * 20 + q * 4) =
                *reinterpret_cast<const float4*>(x + (size_t)grow * D +
                                                 p * KP + q * 4);
        }
        __syncthreads();
#pragma unroll
        for (int q = 0; q < KP / 4; q++) {
            const int k = p * KP + q * 4;
            const float4 w0 =
                *reinterpret_cast<const float4*>(wlds + (k + 0) * 16 + 4 * g);
            const float4 w1 =
                *reinterpret_cast<const float4*>(wlds + (k + 1) * 16 + 4 * g);
            const float4 w2 =
                *reinterpret_cast<const float4*>(wlds + (k + 2) * 16 + 4 * g);
            const float4 w3 =
                *reinterpret_cast<const float4*>(wlds + (k + 3) * 16 + 4 * g);
#pragma unroll
            for (int j = 0; j < 4; j++) {
                const float4 xv = *reinterpret_cast<const float4*>(
                    xlds + (rg + 64 * j) * 20 + q * 4);
                fma4(acc[j], xv.x, w0);
                fma4(acc[j], xv.y, w1);
                fma4(acc[j], xv.z, w2);
                fma4(acc[j], xv.w, w3);
            }
        }
    }

    const float4 b4 = *reinterpret_cast<const float4*>(blds + 4 * g);
#pragma unroll
    for (int j = 0; j < 4; j++) {
        const int grow = row0 + rg + 64 * j;
        if (grow < nrows) {
            float4 o;
            o.x = acc[j].x + b4.x;
            o.y = acc[j].y + b4.y;
            o.z = acc[j].z + b4.z;
            o.w = acc[j].w + b4.w;
            *reinterpret_cast<float4*>(out + (size_t)grow * 16 + 4 * g) = o;
        }
    }
}

// ---------------- CSR construction ----------------
__global__ __launch_bounds__(256) void hist_kernel(const int* __restrict__ dst,
                                                   int* __restrict__ cnt) {
    const int e = blockIdx.x * 256 + threadIdx.x;
    if (e >= ETRAIN) return;
    atomicAdd(cnt + dst[e], 1);
}

__global__ __launch_bounds__(256) void scan1_kernel(const int* __restrict__ in,
                                                    int* __restrict__ out,
                                                    int* __restrict__ bsum,
                                                    int n) {
    __shared__ int s[256];
    const int tid = threadIdx.x;
    const int i = blockIdx.x * 256 + tid;
    const int v = (i < n) ? in[i] : 0;
    s[tid] = v;
    __syncthreads();
#pragma unroll
    for (int off = 1; off < 256; off <<= 1) {
        const int t = (tid >= off) ? s[tid - off] : 0;
        __syncthreads();
        s[tid] += t;
        __syncthreads();
    }
    if (i < n) out[i] = s[tid] - v;
    if (tid == 255) bsum[blockIdx.x] = s[255];
}

__global__ __launch_bounds__(256) void scan2_kernel(int* __restrict__ bsum,
                                                    int nb) {
    __shared__ int s[256];
    const int tid = threadIdx.x;
    int carry = 0;
    for (int base = 0; base < nb; base += 256) {
        const int i = base + tid;
        const int v = (i < nb) ? bsum[i] : 0;
        s[tid] = v;
        __syncthreads();
#pragma unroll
        for (int off = 1; off < 256; off <<= 1) {
            const int t = (tid >= off) ? s[tid - off] : 0;
            __syncthreads();
            s[tid] += t;
            __syncthreads();
        }
        if (i < nb) bsum[i] = s[tid] - v + carry;
        const int tot = s[255];
        __syncthreads();
        carry += tot;
    }
}

__global__ __launch_bounds__(256) void scan3_kernel(int* __restrict__ out,
                                                    const int* __restrict__ bsum,
                                                    int n) {
    const int i = blockIdx.x * 256 + threadIdx.x;
    if (i < n) out[i] += bsum[blockIdx.x];
}

__global__ __launch_bounds__(256) void fill_kernel(
    const int* __restrict__ src, const int* __restrict__ dst,
    const int* __restrict__ et, const int* __restrict__ rowptr,
    int* __restrict__ fc, int* __restrict__ esorted) {
    const int e = blockIdx.x * 256 + threadIdx.x;
    if (e >= ETRAIN) return;
    const int d = dst[e];
    const int pos = rowptr[d] + atomicAdd(fc + d, 1);
    esorted[pos] = src[e] | (et[e] << 24);
}

// ---------------- RGCN phase A: per-relation feature means ----------------
// 16 lanes per node: e = lane>>2 walks edges (stride 4), f = lane&3 owns a
// 16B feature chunk. Coalesced 64B row reads; shfl_xor reduce across e.
template <int IN, bool XH>
__global__ __launch_bounds__(256) void agg_kernel(
    const void* __restrict__ xv, const int* __restrict__ rowptr,
    const int* __restrict__ cnt, const int* __restrict__ esorted,
    float* __restrict__ sx) {
    constexpr int NF = XH ? 8 : 4;  // features owned per lane
    const int gtid = blockIdx.x * 256 + threadIdx.x;
    const int n = gtid >> 4;
    if (n >= NNODES) return;
    const int lane = gtid & 15;
    const int f = lane & 3;
    const int e = lane >> 2;
    const int b = rowptr[n], c = cnt[n];

    float a0[NF], a1[NF];
#pragma unroll
    for (int j = 0; j < NF; j++) {
        a0[j] = 0.f;
        a1[j] = 0.f;
    }

    if constexpr (XH) {
        const f16* x = (const f16*)xv;
        for (int i = e; i < c; i += 4) {
            const int pk = esorted[b + i];
            const int s = pk & 0x00FFFFFF;
            const float w1 = (float)(pk >> 24);
            const float w0 = 1.0f - w1;
            const f16x8 raw = *((const f16x8*)(x + (size_t)s * IN) + f);
#pragma unroll
            for (int j = 0; j < 8; j++) {
                const float xf = (float)raw[j];
                a0[j] = fmaf(w0, xf, a0[j]);
                a1[j] = fmaf(w1, xf, a1[j]);
            }
        }
    } else {
        const float* x = (const float*)xv;
        for (int i = e; i < c; i += 4) {
            const int pk = esorted[b + i];
            const int s = pk & 0x00FFFFFF;
            const float w1 = (float)(pk >> 24);
            const float w0 = 1.0f - w1;
            const float4 xvv = *((const float4*)(x + (size_t)s * IN) + f);
            const float xf[4] = {xvv.x, xvv.y, xvv.z, xvv.w};
#pragma unroll
            for (int j = 0; j < 4; j++) {
                a0[j] = fmaf(w0, xf[j], a0[j]);
                a1[j] = fmaf(w1, xf[j], a1[j]);
            }
        }
    }
    // reduce across the 4 e-lanes (xor masks 4 and 8 stay in the 16-lane group)
#pragma unroll
    for (int m = 4; m <= 8; m <<= 1) {
#pragma unroll
        for (int j = 0; j < NF; j++) {
            a0[j] += __shfl_xor(a0[j], m);
            a1[j] += __shfl_xor(a1[j], m);
        }
    }
    const float inv = 1.0f / fmaxf((float)c, 1.0f);
    float4* o = reinterpret_cast<float4*>(sx + (size_t)n * 2 * IN);
    if constexpr (XH) {
        // lane(e,f) owns features [8f,8f+8). e selects which float4 + relation.
        float4 v;
        if (e == 0) v = make_float4(a0[0], a0[1], a0[2], a0[3]);
        else if (e == 1) v = make_float4(a0[4], a0[5], a0[6], a0[7]);
        else if (e == 2) v = make_float4(a1[0], a1[1], a1[2], a1[3]);
        else v = make_float4(a1[4], a1[5], a1[6], a1[7]);
        v.x *= inv; v.y *= inv; v.z *= inv; v.w *= inv;
        const int half = e >> 1, sub = e & 1;
        o[half * 8 + 2 * f + sub] = v;
    } else {
        if (e < 2) {
            float4 v;
            if (e == 0) v = make_float4(a0[0], a0[1], a0[2], a0[3]);
            else v = make_float4(a1[0], a1[1], a1[2], a1[3]);
            v.x *= inv; v.y *= inv; v.z *= inv; v.w *= inv;
            o[e * 4 + f] = v;
        }
    }
}

// ---------------- RGCN phase B: out = [sx0,sx1,x] @ [W0;W1;root] + bias -----
template <int IN, int OUT, bool RELU, bool INH, bool OUTH>
__global__ __launch_bounds__(256) void combine2_kernel(
    const void* __restrict__ xinp, const float* __restrict__ sx,
    const float* __restrict__ comp, const float* __restrict__ basis,
    const float* __restrict__ root, const float* __restrict__ bias,
    void* __restrict__ outp) {
    constexpr int QP = OUT / 4;
    __shared__ float wl[3 * IN * OUT];  // rows: W0 | W1 | root
    __shared__ float bl[OUT];
    for (int i = threadIdx.x; i < 2 * IN * OUT; i += 256) {
        const int r = i / (IN * OUT);
        const int rem = i - r * IN * OUT;
        float v = 0.f;
#pragma unroll
        for (int bb = 0; bb < 4; bb++)
            v = fmaf(comp[r * 4 + bb], basis[bb * IN * OUT + rem], v);
        wl[i] = v;
    }
    for (int i = threadIdx.x; i < IN * OUT; i += 256)
        wl[2 * IN * OUT + i] = root[i];
    if (threadIdx.x < OUT) bl[threadIdx.x] = bias[threadIdx.x];
    __syncthreads();

    const int gtid = blockIdx.x * 256 + threadIdx.x;
    const int n = gtid / QP;
    const int g = gtid % QP;
    if (n >= NNODES) return;

    float4 acc = *reinterpret_cast<const float4*>(bl + 4 * g);

    const float4* iv1 =
        reinterpret_cast<const float4*>(sx + (size_t)n * (2 * IN));
#pragma unroll
    for (int q = 0; q < 2 * IN / 4; q++) {
        const float4 xv = iv1[q];
        const float* wr = wl + (q * 4) * OUT + 4 * g;
        fma4(acc, xv.x, *reinterpret_cast<const float4*>(wr));
        fma4(acc, xv.y, *reinterpret_cast<const float4*>(wr + OUT));
        fma4(acc, xv.z, *reinterpret_cast<const float4*>(wr + 2 * OUT));
        fma4(acc, xv.w, *reinterpret_cast<const float4*>(wr + 3 * OUT));
    }
    if constexpr (INH) {
        const f16* xin = (const f16*)xinp;
        const f16x8* iv2 = (const f16x8*)(xin + (size_t)n * IN);
#pragma unroll
        for (int q = 0; q < IN / 8; q++) {
            const f16x8 raw = iv2[q];
            const float* wr = wl + (2 * IN + q * 8) * OUT + 4 * g;
#pragma unroll
            for (int j = 0; j < 8; j++)
                fma4(acc, (float)raw[j],
                     *reinterpret_cast<const float4*>(wr + j * OUT));
        }
    } else {
        const float4* iv2 =
            reinterpret_cast<const float4*>((const float*)xinp + (size_t)n * IN);
#pragma unroll
        for (int q = 0; q < IN / 4; q++) {
            const float4 xv = iv2[q];
            const float* wr = wl + (2 * IN + q * 4) * OUT + 4 * g;
            fma4(acc, xv.x, *reinterpret_cast<const float4*>(wr));
            fma4(acc, xv.y, *reinterpret_cast<const float4*>(wr + OUT));
            fma4(acc, xv.z, *reinterpret_cast<const float4*>(wr + 2 * OUT));
            fma4(acc, xv.w, *reinterpret_cast<const float4*>(wr + 3 * OUT));
        }
    }
    if (RELU) {
        acc.x = fmaxf(acc.x, 0.f);
        acc.y = fmaxf(acc.y, 0.f);
        acc.z = fmaxf(acc.z, 0.f);
        acc.w = fmaxf(acc.w, 0.f);
    }
    if constexpr (OUTH) {
        f16x4 hv;
        hv[0] = (f16)acc.x;
        hv[1] = (f16)acc.y;
        hv[2] = (f16)acc.z;
        hv[3] = (f16)acc.w;
        reinterpret_cast<f16x4*>((f16*)outp + (size_t)n * OUT)[g] = hv;
    } else {
        reinterpret_cast<float4*>((float*)outp + (size_t)n * OUT)[g] = acc;
    }
}

// ---------------- decode: score = ((zs @ W[t]) + b[t]) . zd ----------------
// 4 lanes per edge: lane f loads zs/zd chunk f (coalesced 64B per edge),
// computes partial p from its 4 inputs, shfl-reduces p, dots with its zd
// chunk, reduces the scalar.
__global__ __launch_bounds__(256) void decode_kernel(
    const float* __restrict__ z, const int* __restrict__ ei,
    const int* __restrict__ et, const float* __restrict__ wp,
    const float* __restrict__ bp, const float* __restrict__ wm,
    const float* __restrict__ bm, float* __restrict__ out, int E) {
    __shared__ float wl[2 * 256];
    __shared__ float bl[2 * 16];
    {
        const int i = threadIdx.x;
        wl[i] = wp[i];
        wl[256 + i] = wm[i];
        if (i < 16) {
            bl[i] = bp[i];
            bl[16 + i] = bm[i];
        }
    }
    __syncthreads();

    const int gtid = blockIdx.x * 256 + threadIdx.x;
    const int e = gtid >> 2;
    const int f = gtid & 3;
    if (e >= E) return;
    const int s = ei[e], d = ei[e + E], t = et[e];

    const float4 zs = reinterpret_cast<const float4*>(z + (size_t)s * 16)[f];
    const float4 zd = reinterpret_cast<const float4*>(z + (size_t)d * 16)[f];

    const float* W = wl + t * 256;
    float4 p[4];
    if (f == 0) {
#pragma unroll
        for (int g = 0; g < 4; g++)
            p[g] = reinterpret_cast<const float4*>(bl + t * 16)[g];
    } else {
#pragma unroll
        for (int g = 0; g < 4; g++) p[g] = make_float4(0.f, 0.f, 0.f, 0.f);
    }
    const float xs[4] = {zs.x, zs.y, zs.z, zs.w};
#pragma unroll
    for (int c = 0; c < 4; c++) {
        const float4* wr =
            reinterpret_cast<const float4*>(W + (4 * f + c) * 16);
#pragma unroll
        for (int g = 0; g < 4; g++) fma4(p[g], xs[c], wr[g]);
    }
    float* pp = reinterpret_cast<float*>(p);
#pragma unroll
    for (int m = 1; m <= 2; m <<= 1) {
#pragma unroll
        for (int j = 0; j < 16; j++) pp[j] += __shfl_xor(pp[j], m);
    }
    float4 pf;
    if (f == 0) pf = p[0];
    else if (f == 1) pf = p[1];
    else if (f == 2) pf = p[2];
    else pf = p[3];
    float sc = pf.x * zd.x + pf.y * zd.y + pf.z * zd.z + pf.w * zd.w;
    sc += __shfl_xor(sc, 1);
    sc += __shfl_xor(sc, 2);
    if (f == 0) out[e] = sc;
}

extern "C" void kernel_launch(void* const* d_in, const int* in_sizes, int n_in,
                              void* d_out, int out_size, void* d_ws,
                              size_t ws_size, hipStream_t stream) {
    const float* x_paper = (const float*)d_in[0];
    const float* x_mesh = (const float*)d_in[1];
    const float* tp_w = (const float*)d_in[2];
    const float* tp_b = (const float*)d_in[3];
    const float* tm_w = (const float*)d_in[4];
    const float* tm_b = (const float*)d_in[5];
    const float* comp1 = (const float*)d_in[6];
    const float* basis1 = (const float*)d_in[7];
    const float* root1 = (const float*)d_in[8];
    const float* bias1 = (const float*)d_in[9];
    const float* comp2 = (const float*)d_in[10];
    const float* basis2 = (const float*)d_in[11];
    const float* root2 = (const float*)d_in[12];
    const float* bias2 = (const float*)d_in[13];
    const float* comp3 = (const float*)d_in[14];
    const float* basis3 = (const float*)d_in[15];
    const float* root3 = (const float*)d_in[16];
    const float* bias3 = (const float*)d_in[17];
    const float* dpp_w = (const float*)d_in[18];
    const float* dpp_b = (const float*)d_in[19];
    const float* dpm_w = (const float*)d_in[20];
    const float* dpm_b = (const float*)d_in[21];
    const int* tei = (const int*)d_in[22];
    const int* tet = (const int*)d_in[23];
    const int* pei = (const int*)d_in[24];
    const int* pet = (const int*)d_in[25];
    const int* nei = (const int*)d_in[26];
    const int* net = (const int*)d_in[27];
    float* out = (float*)d_out;

    // workspace layout (floats), with live-range overlays:
    //   R1 (32N): h1 (fp16, first 16N f-equiv), later z fp32 (first 16N)
    //   R2 (32N): xfeat fp32 (first 16N), later h2 (fp16)
    //   R3 (64N): sx fp32 (per-layer scratch)
    float* ws = (float*)d_ws;
    float* R1 = ws;
    float* R2 = R1 + (size_t)NNODES * 32;
    float* R3 = R2 + (size_t)NNODES * 32;
    float* xfeat = R2;
    f16* h1h = (f16*)R1;
    f16* h2h = (f16*)R2;
    float* sx = R3;
    float* z = R1;

    int* rowptr = (int*)(R3 + (size_t)NNODES * 64);  // N
    int* ecnt = rowptr + NNODES;                     // N
    int* fc = ecnt + NNODES;                         // N
    int* esorted = fc + NNODES;                      // E_TRAIN
    int* bsum = esorted + ETRAIN;                    // ~1K

    const int* tsrc = tei;
    const int* tdst = tei + ETRAIN;

    const int eblocks = (ETRAIN + 255) / 256;
    const int nb = (NNODES + 255) / 256;            // 899
    const int aggb = (NNODES * 16 + 255) / 256;     // 14375

    // ---- encode ----
    encode_kernel<512><<<(NPAPER + 255) / 256, 256, 0, stream>>>(
        x_paper, tp_w, tp_b, xfeat, NPAPER);
    encode_kernel<128><<<(NMESH + 255) / 256, 256, 0, stream>>>(
        x_mesh, tm_w, tm_b, xfeat + (size_t)NPAPER * 16, NMESH);

    // ---- CSR build (once; reused by all 3 layers) ----
    hipMemsetAsync(ecnt, 0, (size_t)NNODES * 4, stream);
    hipMemsetAsync(fc, 0, (size_t)NNODES * 4, stream);
    hist_kernel<<<eblocks, 256, 0, stream>>>(tdst, ecnt);
    scan1_kernel<<<nb, 256, 0, stream>>>(ecnt, rowptr, bsum, NNODES);
    scan2_kernel<<<1, 256, 0, stream>>>(bsum, nb);
    scan3_kernel<<<nb, 256, 0, stream>>>(rowptr, bsum, NNODES);
    fill_kernel<<<eblocks, 256, 0, stream>>>(tsrc, tdst, tet, rowptr, fc,
                                             esorted);

    // ---- layer 1: 16 -> 32, relu (x fp32, out fp16) ----
    agg_kernel<16, false><<<aggb, 256, 0, stream>>>(xfeat, rowptr, ecnt,
                                                    esorted, sx);
    combine2_kernel<16, 32, true, false, true>
        <<<(NNODES * 8 + 255) / 256, 256, 0, stream>>>(xfeat, sx, comp1,
                                                       basis1, root1, bias1,
                                                       h1h);
    // ---- layer 2: 32 -> 32, relu (fp16 in, fp16 out) ----
    agg_kernel<32, true><<<aggb, 256, 0, stream>>>(h1h, rowptr, ecnt, esorted,
                                                   sx);
    combine2_kernel<32, 32, true, true, true>
        <<<(NNODES * 8 + 255) / 256, 256, 0, stream>>>(h1h, sx, comp2, basis2,
                                                       root2, bias2, h2h);
    // ---- layer 3: 32 -> 16, no relu (fp16 in, fp32 out) ----
    agg_kernel<32, true><<<aggb, 256, 0, stream>>>(h2h, rowptr, ecnt, esorted,
                                                   sx);
    combine2_kernel<32, 16, false, true, false>
        <<<(NNODES * 4 + 255) / 256, 256, 0, stream>>>(h2h, sx, comp3, basis3,
                                                       root3, bias3, z);

    // ---- decode (4 lanes per edge) ----
    decode_kernel<<<(EPOS * 4 + 255) / 256, 256, 0, stream>>>(
        z, pei, pet, dpp_w, dpp_b, dpm_w, dpm_b, out, EPOS);
    decode_kernel<<<(ENEG * 4 + 255) / 256, 256, 0, stream>>>(
        z, nei, net, dpp_w, dpp_b, dpm_w, dpm_b, out + EPOS, ENEG);
}

// Round 2
// 1151.668 us; speedup vs baseline: 1.0756x; 1.0052x over previous
//
#include <hip/hip_runtime.h>

#define NPAPER 200000
#define NMESH  30000
#define NNODES 230000
#define ETRAIN 2000000
#define EPOS   500000
#define ENEG   500000

typedef _Float16 f16;
typedef __attribute__((ext_vector_type(8))) _Float16 f16x8;
typedef __attribute__((ext_vector_type(4))) _Float16 f16x4;

__device__ __forceinline__ void fma4(float4& a, float s, const float4 w) {
    a.x = fmaf(s, w.x, a.x);
    a.y = fmaf(s, w.y, a.y);
    a.z = fmaf(s, w.z, a.z);
    a.w = fmaf(s, w.w, a.w);
}

// ---------------- encode: out[row][0:16] = x[row][:] @ W + b ----------------
template <int D>
__global__ __launch_bounds__(256) void encode_kernel(
    const float* __restrict__ x, const float* __restrict__ w,
    const float* __restrict__ bias, float* __restrict__ out, int nrows) {
    constexpr int KP = 16;
    __shared__ float wlds[D * 16];       // [k][16]
    __shared__ float xlds[256 * 20];     // [row][KP] stride 20 floats
    __shared__ float blds[16];

    for (int i = threadIdx.x; i < D * 4; i += 256)
        reinterpret_cast<float4*>(wlds)[i] =
            reinterpret_cast<const float4*>(w)[i];
    if (threadIdx.x < 16) blds[threadIdx.x] = bias[threadIdx.x];

    const int g = threadIdx.x & 3;
    const int rg = threadIdx.x >> 2;  // 0..63
    const int row0 = blockIdx.x * 256;

    float4 acc[4];
#pragma unroll
    for (int j = 0; j < 4; j++) acc[j] = make_float4(0.f, 0.f, 0.f, 0.f);

    for (int p = 0; p < D / KP; p++) {
        __syncthreads();
        for (int i = threadIdx.x; i < 1024; i += 256) {
            const int rr = i >> 2, q = i & 3;
            const int grow = min(row0 + rr, nrows - 1);
            *reinterpret_cast<float4*>(xlds + rr * 20 + q * 4) =
                *reinterpret_cast<const float4*>(x + (size_t)grow * D +
                                                 p * KP + q * 4);
        }
        __syncthreads();
#pragma unroll
        for (int q = 0; q < KP / 4; q++) {
            const int k = p * KP + q * 4;
            const float4 w0 =
                *reinterpret_cast<const float4*>(wlds + (k + 0) * 16 + 4 * g);
            const float4 w1 =
                *reinterpret_cast<const float4*>(wlds + (k + 1) * 16 + 4 * g);
            const float4 w2 =
                *reinterpret_cast<const float4*>(wlds + (k + 2) * 16 + 4 * g);
            const float4 w3 =
                *reinterpret_cast<const float4*>(wlds + (k + 3) * 16 + 4 * g);
#pragma unroll
            for (int j = 0; j < 4; j++) {
                const float4 xv = *reinterpret_cast<const float4*>(
                    xlds + (rg + 64 * j) * 20 + q * 4);
                fma4(acc[j], xv.x, w0);
                fma4(acc[j], xv.y, w1);
                fma4(acc[j], xv.z, w2);
                fma4(acc[j], xv.w, w3);
            }
        }
    }

    const float4 b4 = *reinterpret_cast<const float4*>(blds + 4 * g);
#pragma unroll
    for (int j = 0; j < 4; j++) {
        const int grow = row0 + rg + 64 * j;
        if (grow < nrows) {
            float4 o;
            o.x = acc[j].x + b4.x;
            o.y = acc[j].y + b4.y;
            o.z = acc[j].z + b4.z;
            o.w = acc[j].w + b4.w;
            *reinterpret_cast<float4*>(out + (size_t)grow * 16 + 4 * g) = o;
        }
    }
}

// ---------------- CSR construction ----------------
__global__ __launch_bounds__(256) void hist_kernel(const int* __restrict__ dst,
                                                   int* __restrict__ cnt) {
    const int e = blockIdx.x * 256 + threadIdx.x;
    if (e >= ETRAIN) return;
    atomicAdd(cnt + dst[e], 1);
}

__global__ __launch_bounds__(256) void scan1_kernel(const int* __restrict__ in,
                                                    int* __restrict__ out,
                                                    int* __restrict__ bsum,
                                                    int n) {
    __shared__ int s[256];
    const int tid = threadIdx.x;
    const int i = blockIdx.x * 256 + tid;
    const int v = (i < n) ? in[i] : 0;
    s[tid] = v;
    __syncthreads();
#pragma unroll
    for (int off = 1; off < 256; off <<= 1) {
        const int t = (tid >= off) ? s[tid - off] : 0;
        __syncthreads();
        s[tid] += t;
        __syncthreads();
    }
    if (i < n) out[i] = s[tid] - v;
    if (tid == 255) bsum[blockIdx.x] = s[255];
}

__global__ __launch_bounds__(256) void scan2_kernel(int* __restrict__ bsum,
                                                    int nb) {
    __shared__ int s[256];
    const int tid = threadIdx.x;
    int carry = 0;
    for (int base = 0; base < nb; base += 256) {
        const int i = base + tid;
        const int v = (i < nb) ? bsum[i] : 0;
        s[tid] = v;
        __syncthreads();
#pragma unroll
        for (int off = 1; off < 256; off <<= 1) {
            const int t = (tid >= off) ? s[tid - off] : 0;
            __syncthreads();
            s[tid] += t;
            __syncthreads();
        }
        if (i < nb) bsum[i] = s[tid] - v + carry;
        const int tot = s[255];
        __syncthreads();
        carry += tot;
    }
}

// fill: final CSR position = rowptr[d] (block-local excl) + bsum[d>>8] + fc++
__global__ __launch_bounds__(256) void fill_kernel(
    const int* __restrict__ src, const int* __restrict__ dst,
    const int* __restrict__ et, const int* __restrict__ rowptr,
    const int* __restrict__ bsum, int* __restrict__ fc,
    int* __restrict__ esorted) {
    const int e = blockIdx.x * 256 + threadIdx.x;
    if (e >= ETRAIN) return;
    const int d = dst[e];
    const int pos = rowptr[d] + bsum[d >> 8] + atomicAdd(fc + d, 1);
    esorted[pos] = src[e] | (et[e] << 24);
}

// ---------------- per-node transform: t_r = x @ W_r (fp16), r = x@root+b ----
// thread (n,g) owns 4 output cols; W0|W1|root staged in LDS.
template <int IN, int OUT, bool INH>
__global__ __launch_bounds__(256) void transform_kernel(
    const void* __restrict__ xinp, const float* __restrict__ comp,
    const float* __restrict__ basis, const float* __restrict__ root,
    const float* __restrict__ bias, f16* __restrict__ tcat,
    float* __restrict__ rbuf) {
    constexpr int QP = OUT / 4;
    __shared__ float wl[3 * IN * OUT];  // W0 | W1 | root
    __shared__ float bl[OUT];
    for (int i = threadIdx.x; i < 2 * IN * OUT; i += 256) {
        const int rr = i / (IN * OUT);
        const int rem = i - rr * IN * OUT;
        float v = 0.f;
#pragma unroll
        for (int bb = 0; bb < 4; bb++)
            v = fmaf(comp[rr * 4 + bb], basis[bb * IN * OUT + rem], v);
        wl[i] = v;
    }
    for (int i = threadIdx.x; i < IN * OUT; i += 256)
        wl[2 * IN * OUT + i] = root[i];
    if (threadIdx.x < OUT) bl[threadIdx.x] = bias[threadIdx.x];
    __syncthreads();

    const int gtid = blockIdx.x * 256 + threadIdx.x;
    const int n = gtid / QP;
    const int g = gtid % QP;
    if (n >= NNODES) return;

    float4 a0 = make_float4(0.f, 0.f, 0.f, 0.f);
    float4 a1 = a0;
    float4 ar = *reinterpret_cast<const float4*>(bl + 4 * g);

    if constexpr (INH) {
        const f16* xin = (const f16*)xinp + (size_t)n * IN;
#pragma unroll
        for (int q = 0; q < IN / 8; q++) {
            const f16x8 raw = reinterpret_cast<const f16x8*>(xin)[q];
#pragma unroll
            for (int j = 0; j < 8; j++) {
                const float xv = (float)raw[j];
                const float* w0 = wl + (q * 8 + j) * OUT + 4 * g;
                fma4(a0, xv, *reinterpret_cast<const float4*>(w0));
                fma4(a1, xv, *reinterpret_cast<const float4*>(w0 + IN * OUT));
                fma4(ar, xv,
                     *reinterpret_cast<const float4*>(w0 + 2 * IN * OUT));
            }
        }
    } else {
        const float* xin = (const float*)xinp + (size_t)n * IN;
#pragma unroll
        for (int q = 0; q < IN / 4; q++) {
            const float4 xv4 = reinterpret_cast<const float4*>(xin)[q];
            const float xs[4] = {xv4.x, xv4.y, xv4.z, xv4.w};
#pragma unroll
            for (int j = 0; j < 4; j++) {
                const float* w0 = wl + (q * 4 + j) * OUT + 4 * g;
                fma4(a0, xs[j], *reinterpret_cast<const float4*>(w0));
                fma4(a1, xs[j],
                     *reinterpret_cast<const float4*>(w0 + IN * OUT));
                fma4(ar, xs[j],
                     *reinterpret_cast<const float4*>(w0 + 2 * IN * OUT));
            }
        }
    }
    f16x4 t0, t1;
    t0[0] = (f16)a0.x; t0[1] = (f16)a0.y; t0[2] = (f16)a0.z; t0[3] = (f16)a0.w;
    t1[0] = (f16)a1.x; t1[1] = (f16)a1.y; t1[2] = (f16)a1.z; t1[3] = (f16)a1.w;
    f16* trow = tcat + (size_t)n * 2 * OUT;
    reinterpret_cast<f16x4*>(trow)[g] = t0;
    reinterpret_cast<f16x4*>(trow + OUT)[g] = t1;
    reinterpret_cast<float4*>(rbuf + (size_t)n * OUT)[g] = ar;
}

// ---------------- agg + root fuse: h[n] = act(mean_gather t + r[n]) --------
// 32 lanes/node: e = lane>>2 walks edges (stride 8), f = lane&3 owns OUT/4
// contiguous features. Gather = one 16B (or 8B) load per lane, 64B/32B per
// edge total, coalesced. shfl_xor reduce over e; epilogue by e<2 (or e==0).
template <int OUT, bool RELU, bool OUTH>
__global__ __launch_bounds__(256) void aggroot_kernel(
    const f16* __restrict__ tcat, const float* __restrict__ rbuf,
    const int* __restrict__ rowptr, const int* __restrict__ bsum,
    const int* __restrict__ cnt, const int* __restrict__ esorted,
    void* __restrict__ outp) {
    constexpr int NF = OUT / 4;  // features per f-lane
    const int gtid = blockIdx.x * 256 + threadIdx.x;
    const int n = gtid >> 5;
    if (n >= NNODES) return;
    const int lane = gtid & 31;
    const int f = lane & 3;
    const int e = lane >> 2;  // 0..7
    const int b = rowptr[n] + bsum[n >> 8];
    const int c = cnt[n];

    float a[NF];
#pragma unroll
    for (int j = 0; j < NF; j++) a[j] = 0.f;

    int i = e;
    int pk = (i < c) ? esorted[b + i] : 0;
    while (i < c) {
        const int in2 = i + 8;
        const int pkn = (in2 < c) ? esorted[b + in2] : 0;
        const int s = pk & 0x00FFFFFF;
        const int t = pk >> 24;
        const f16* row = tcat + ((size_t)s * 2 + t) * OUT + f * NF;
        if constexpr (NF == 8) {
            const f16x8 raw = *reinterpret_cast<const f16x8*>(row);
#pragma unroll
            for (int j = 0; j < 8; j++) a[j] += (float)raw[j];
        } else {
            const f16x4 raw = *reinterpret_cast<const f16x4*>(row);
#pragma unroll
            for (int j = 0; j < 4; j++) a[j] += (float)raw[j];
        }
        pk = pkn;
        i = in2;
    }
#pragma unroll
    for (int m = 4; m <= 16; m <<= 1) {
#pragma unroll
        for (int j = 0; j < NF; j++) a[j] += __shfl_xor(a[j], m);
    }
    const float inv = 1.0f / fmaxf((float)c, 1.0f);
    if constexpr (NF == 8) {
        if (e < 2) {
            const int off = f * 8 + e * 4;
            const float4 rv =
                *reinterpret_cast<const float4*>(rbuf + (size_t)n * OUT + off);
            float4 v;
            v.x = fmaf(a[e * 4 + 0], inv, rv.x);
            v.y = fmaf(a[e * 4 + 1], inv, rv.y);
            v.z = fmaf(a[e * 4 + 2], inv, rv.z);
            v.w = fmaf(a[e * 4 + 3], inv, rv.w);
            if (RELU) {
                v.x = fmaxf(v.x, 0.f);
                v.y = fmaxf(v.y, 0.f);
                v.z = fmaxf(v.z, 0.f);
                v.w = fmaxf(v.w, 0.f);
            }
            if constexpr (OUTH) {
                f16x4 hv;
                hv[0] = (f16)v.x; hv[1] = (f16)v.y;
                hv[2] = (f16)v.z; hv[3] = (f16)v.w;
                *reinterpret_cast<f16x4*>((f16*)outp + (size_t)n * OUT + off) =
                    hv;
            } else {
                *reinterpret_cast<float4*>((float*)outp + (size_t)n * OUT +
                                           off) = v;
            }
        }
    } else {
        if (e == 0) {
            const int off = f * 4;
            const float4 rv =
                *reinterpret_cast<const float4*>(rbuf + (size_t)n * OUT + off);
            float4 v;
            v.x = fmaf(a[0], inv, rv.x);
            v.y = fmaf(a[1], inv, rv.y);
            v.z = fmaf(a[2], inv, rv.z);
            v.w = fmaf(a[3], inv, rv.w);
            if (RELU) {
                v.x = fmaxf(v.x, 0.f);
                v.y = fmaxf(v.y, 0.f);
                v.z = fmaxf(v.z, 0.f);
                v.w = fmaxf(v.w, 0.f);
            }
            if constexpr (OUTH) {
                f16x4 hv;
                hv[0] = (f16)v.x; hv[1] = (f16)v.y;
                hv[2] = (f16)v.z; hv[3] = (f16)v.w;
                *reinterpret_cast<f16x4*>((f16*)outp + (size_t)n * OUT + off) =
                    hv;
            } else {
                *reinterpret_cast<float4*>((float*)outp + (size_t)n * OUT +
                                           off) = v;
            }
        }
    }
}

// ---------------- decode: score = ((zs @ W[t]) + b[t]) . zd ----------------
// merged pos+neg; 4 lanes per edge, coalesced 64B row pairs, shfl reduce.
__global__ __launch_bounds__(256) void decode_kernel(
    const float* __restrict__ z, const int* __restrict__ pei,
    const int* __restrict__ pet, const int* __restrict__ nei,
    const int* __restrict__ net, const float* __restrict__ wp,
    const float* __restrict__ bp, const float* __restrict__ wm,
    const float* __restrict__ bm, float* __restrict__ out) {
    __shared__ float wl[2 * 256];
    __shared__ float bl[2 * 16];
    {
        const int i = threadIdx.x;
        wl[i] = wp[i];
        wl[256 + i] = wm[i];
        if (i < 16) {
            bl[i] = bp[i];
            bl[16 + i] = bm[i];
        }
    }
    __syncthreads();

    const int gtid = blockIdx.x * 256 + threadIdx.x;
    const int e = gtid >> 2;
    const int f = gtid & 3;
    if (e >= EPOS + ENEG) return;
    int s, d, t;
    if (e < EPOS) {
        s = pei[e];
        d = pei[e + EPOS];
        t = pet[e];
    } else {
        const int ee = e - EPOS;
        s = nei[ee];
        d = nei[ee + ENEG];
        t = net[ee];
    }

    const float4 zs = reinterpret_cast<const float4*>(z + (size_t)s * 16)[f];
    const float4 zd = reinterpret_cast<const float4*>(z + (size_t)d * 16)[f];

    const float* W = wl + t * 256;
    float4 p[4];
    if (f == 0) {
#pragma unroll
        for (int g = 0; g < 4; g++)
            p[g] = reinterpret_cast<const float4*>(bl + t * 16)[g];
    } else {
#pragma unroll
        for (int g = 0; g < 4; g++) p[g] = make_float4(0.f, 0.f, 0.f, 0.f);
    }
    const float xs[4] = {zs.x, zs.y, zs.z, zs.w};
#pragma unroll
    for (int c = 0; c < 4; c++) {
        const float4* wr =
            reinterpret_cast<const float4*>(W + (4 * f + c) * 16);
#pragma unroll
        for (int g = 0; g < 4; g++) fma4(p[g], xs[c], wr[g]);
    }
    float* pp = reinterpret_cast<float*>(p);
#pragma unroll
    for (int m = 1; m <= 2; m <<= 1) {
#pragma unroll
        for (int j = 0; j < 16; j++) pp[j] += __shfl_xor(pp[j], m);
    }
    float4 pf;
    if (f == 0) pf = p[0];
    else if (f == 1) pf = p[1];
    else if (f == 2) pf = p[2];
    else pf = p[3];
    float sc = pf.x * zd.x + pf.y * zd.y + pf.z * zd.z + pf.w * zd.w;
    sc += __shfl_xor(sc, 1);
    sc += __shfl_xor(sc, 2);
    if (f == 0) out[e] = sc;
}

extern "C" void kernel_launch(void* const* d_in, const int* in_sizes, int n_in,
                              void* d_out, int out_size, void* d_ws,
                              size_t ws_size, hipStream_t stream) {
    const float* x_paper = (const float*)d_in[0];
    const float* x_mesh = (const float*)d_in[1];
    const float* tp_w = (const float*)d_in[2];
    const float* tp_b = (const float*)d_in[3];
    const float* tm_w = (const float*)d_in[4];
    const float* tm_b = (const float*)d_in[5];
    const float* comp1 = (const float*)d_in[6];
    const float* basis1 = (const float*)d_in[7];
    const float* root1 = (const float*)d_in[8];
    const float* bias1 = (const float*)d_in[9];
    const float* comp2 = (const float*)d_in[10];
    const float* basis2 = (const float*)d_in[11];
    const float* root2 = (const float*)d_in[12];
    const float* bias2 = (const float*)d_in[13];
    const float* comp3 = (const float*)d_in[14];
    const float* basis3 = (const float*)d_in[15];
    const float* root3 = (const float*)d_in[16];
    const float* bias3 = (const float*)d_in[17];
    const float* dpp_w = (const float*)d_in[18];
    const float* dpp_b = (const float*)d_in[19];
    const float* dpm_w = (const float*)d_in[20];
    const float* dpm_b = (const float*)d_in[21];
    const int* tei = (const int*)d_in[22];
    const int* tet = (const int*)d_in[23];
    const int* pei = (const int*)d_in[24];
    const int* pet = (const int*)d_in[25];
    const int* nei = (const int*)d_in[26];
    const int* net = (const int*)d_in[27];
    float* out = (float*)d_out;

    // workspace layout (in float units), no live-range overlap:
    const size_t N = NNODES;
    float* ws = (float*)d_ws;
    float* xfeat = ws;                      // 16N fp32
    float* z = ws + 16 * N;                 // 16N fp32
    float* rbuf = ws + 32 * N;              // 32N fp32 (max OUT)
    f16* tcat = (f16*)(ws + 64 * N);        // 2*32 fp16/node = 32N fl-equiv
    f16* h1 = (f16*)(ws + 96 * N);          // 32 fp16/node = 16N fl-equiv
    f16* h2 = (f16*)(ws + 112 * N);         // 16N fl-equiv
    int* rowptr = (int*)(ws + 128 * N);     // N
    int* ecnt = rowptr + N;                 // N
    int* fc = ecnt + N;                     // N (adjacent to ecnt: one memset)
    int* esorted = fc + N;                  // E_TRAIN
    int* bsum = esorted + ETRAIN;           // ~900

    const int* tsrc = tei;
    const int* tdst = tei + ETRAIN;

    const int eblocks = (ETRAIN + 255) / 256;
    const int nb = (NNODES + 255) / 256;             // 899
    const int aggb = (NNODES * 32 + 255) / 256;      // 28750

    // ---- encode ----
    encode_kernel<512><<<(NPAPER + 255) / 256, 256, 0, stream>>>(
        x_paper, tp_w, tp_b, xfeat, NPAPER);
    encode_kernel<128><<<(NMESH + 255) / 256, 256, 0, stream>>>(
        x_mesh, tm_w, tm_b, xfeat + (size_t)NPAPER * 16, NMESH);

    // ---- CSR build (once; reused by all 3 layers) ----
    hipMemsetAsync(ecnt, 0, (size_t)2 * NNODES * 4, stream);  // ecnt + fc
    hist_kernel<<<eblocks, 256, 0, stream>>>(tdst, ecnt);
    scan1_kernel<<<nb, 256, 0, stream>>>(ecnt, rowptr, bsum, NNODES);
    scan2_kernel<<<1, 256, 0, stream>>>(bsum, nb);
    fill_kernel<<<eblocks, 256, 0, stream>>>(tsrc, tdst, tet, rowptr, bsum,
                                             fc, esorted);

    // ---- layer 1: 16 -> 32, relu ----
    transform_kernel<16, 32, false>
        <<<(NNODES * 8 + 255) / 256, 256, 0, stream>>>(xfeat, comp1, basis1,
                                                       root1, bias1, tcat,
                                                       rbuf);
    aggroot_kernel<32, true, true><<<aggb, 256, 0, stream>>>(
        tcat, rbuf, rowptr, bsum, ecnt, esorted, h1);

    // ---- layer 2: 32 -> 32, relu ----
    transform_kernel<32, 32, true>
        <<<(NNODES * 8 + 255) / 256, 256, 0, stream>>>(h1, comp2, basis2,
                                                       root2, bias2, tcat,
                                                       rbuf);
    aggroot_kernel<32, true, true><<<aggb, 256, 0, stream>>>(
        tcat, rbuf, rowptr, bsum, ecnt, esorted, h2);

    // ---- layer 3: 32 -> 16, no relu, fp32 out ----
    transform_kernel<32, 16, true>
        <<<(NNODES * 4 + 255) / 256, 256, 0, stream>>>(h2, comp3, basis3,
                                                       root3, bias3, tcat,
                                                       rbuf);
    aggroot_kernel<16, false, false><<<aggb, 256, 0, stream>>>(
        tcat, rbuf, rowptr, bsum, ecnt, esorted, z);

    // ---- decode (merged pos+neg, 4 lanes per edge) ----
    decode_kernel<<<((EPOS + ENEG) * 4 + 255) / 256, 256, 0, stream>>>(
        z, pei, pet, nei, net, dpp_w, dpp_b, dpm_w, dpm_b, out);
}

// Round 3
// 1143.717 us; speedup vs baseline: 1.0831x; 1.0070x over previous
//
#include <hip/hip_runtime.h>

#define NPAPER 200000
#define NMESH  30000
#define NNODES 230000
#define ETRAIN 2000000
#define EPOS   500000
#define ENEG   500000

typedef _Float16 f16;
typedef __attribute__((ext_vector_type(8))) _Float16 f16x8;
typedef __attribute__((ext_vector_type(4))) _Float16 f16x4;

__device__ __forceinline__ void fma4(float4& a, float s, const float4 w) {
    a.x = fmaf(s, w.x, a.x);
    a.y = fmaf(s, w.y, a.y);
    a.z = fmaf(s, w.z, a.z);
    a.w = fmaf(s, w.w, a.w);
}

// ---------------- encode: out[row][0:16] = x[row][:] @ W + b ----------------
template <int D>
__global__ __launch_bounds__(256) void encode_kernel(
    const float* __restrict__ x, const float* __restrict__ w,
    const float* __restrict__ bias, float* __restrict__ out, int nrows) {
    constexpr int KP = 16;
    __shared__ float wlds[D * 16];       // [k][16]
    __shared__ float xlds[256 * 20];     // [row][KP] stride 20 floats
    __shared__ float blds[16];

    for (int i = threadIdx.x; i < D * 4; i += 256)
        reinterpret_cast<float4*>(wlds)[i] =
            reinterpret_cast<const float4*>(w)[i];
    if (threadIdx.x < 16) blds[threadIdx.x] = bias[threadIdx.x];

    const int g = threadIdx.x & 3;
    const int rg = threadIdx.x >> 2;  // 0..63
    const int row0 = blockIdx.x * 256;

    float4 acc[4];
#pragma unroll
    for (int j = 0; j < 4; j++) acc[j] = make_float4(0.f, 0.f, 0.f, 0.f);

    for (int p = 0; p < D / KP; p++) {
        __syncthreads();
        for (int i = threadIdx.x; i < 1024; i += 256) {
            const int rr = i >> 2, q = i & 3;
            const int grow = min(row0 + rr, nrows - 1);
            *reinterpret_cast<float4*>(xlds + rr * 20 + q * 4) =
                *reinterpret_cast<const float4*>(x + (size_t)grow * D +
                                                 p * KP + q * 4);
        }
        __syncthreads();
#pragma unroll
        for (int q = 0; q < KP / 4; q++) {
            const int k = p * KP + q * 4;
            const float4 w0 =
                *reinterpret_cast<const float4*>(wlds + (k + 0) * 16 + 4 * g);
            const float4 w1 =
                *reinterpret_cast<const float4*>(wlds + (k + 1) * 16 + 4 * g);
            const float4 w2 =
                *reinterpret_cast<const float4*>(wlds + (k + 2) * 16 + 4 * g);
            const float4 w3 =
                *reinterpret_cast<const float4*>(wlds + (k + 3) * 16 + 4 * g);
#pragma unroll
            for (int j = 0; j < 4; j++) {
                const float4 xv = *reinterpret_cast<const float4*>(
                    xlds + (rg + 64 * j) * 20 + q * 4);
                fma4(acc[j], xv.x, w0);
                fma4(acc[j], xv.y, w1);
                fma4(acc[j], xv.z, w2);
                fma4(acc[j], xv.w, w3);
            }
        }
    }

    const float4 b4 = *reinterpret_cast<const float4*>(blds + 4 * g);
#pragma unroll
    for (int j = 0; j < 4; j++) {
        const int grow = row0 + rg + 64 * j;
        if (grow < nrows) {
            float4 o;
            o.x = acc[j].x + b4.x;
            o.y = acc[j].y + b4.y;
            o.z = acc[j].z + b4.z;
            o.w = acc[j].w + b4.w;
            *reinterpret_cast<float4*>(out + (size_t)grow * 16 + 4 * g) = o;
        }
    }
}

// ---------------- CSR construction ----------------
__global__ __launch_bounds__(256) void hist_kernel(const int* __restrict__ dst,
                                                   int* __restrict__ cnt) {
    const int e = blockIdx.x * 256 + threadIdx.x;
    if (e >= ETRAIN) return;
    atomicAdd(cnt + dst[e], 1);
}

__global__ __launch_bounds__(256) void scan1_kernel(const int* __restrict__ in,
                                                    int* __restrict__ out,
                                                    int* __restrict__ bsum,
                                                    int n) {
    __shared__ int s[256];
    const int tid = threadIdx.x;
    const int i = blockIdx.x * 256 + tid;
    const int v = (i < n) ? in[i] : 0;
    s[tid] = v;
    __syncthreads();
#pragma unroll
    for (int off = 1; off < 256; off <<= 1) {
        const int t = (tid >= off) ? s[tid - off] : 0;
        __syncthreads();
        s[tid] += t;
        __syncthreads();
    }
    if (i < n) out[i] = s[tid] - v;
    if (tid == 255) bsum[blockIdx.x] = s[255];
}

__global__ __launch_bounds__(256) void scan2_kernel(int* __restrict__ bsum,
                                                    int nb) {
    __shared__ int s[256];
    const int tid = threadIdx.x;
    int carry = 0;
    for (int base = 0; base < nb; base += 256) {
        const int i = base + tid;
        const int v = (i < nb) ? bsum[i] : 0;
        s[tid] = v;
        __syncthreads();
#pragma unroll
        for (int off = 1; off < 256; off <<= 1) {
            const int t = (tid >= off) ? s[tid - off] : 0;
            __syncthreads();
            s[tid] += t;
            __syncthreads();
        }
        if (i < nb) bsum[i] = s[tid] - v + carry;
        const int tot = s[255];
        __syncthreads();
        carry += tot;
    }
}

// fill: final CSR position = rowptr[d] (block-local excl) + bsum[d>>8] + fc++
__global__ __launch_bounds__(256) void fill_kernel(
    const int* __restrict__ src, const int* __restrict__ dst,
    const int* __restrict__ et, const int* __restrict__ rowptr,
    const int* __restrict__ bsum, int* __restrict__ fc,
    int* __restrict__ esorted) {
    const int e = blockIdx.x * 256 + threadIdx.x;
    if (e >= ETRAIN) return;
    const int d = dst[e];
    const int pos = rowptr[d] + bsum[d >> 8] + atomicAdd(fc + d, 1);
    esorted[pos] = src[e] | (et[e] << 24);
}

// ---------------- per-node transform: t_r = x @ W_r (fp16), r = x@root+b ----
// thread (n,g) owns 4 output cols; W0|W1|root staged in LDS. rbuf in fp16.
template <int IN, int OUT, bool INH>
__global__ __launch_bounds__(256) void transform_kernel(
    const void* __restrict__ xinp, const float* __restrict__ comp,
    const float* __restrict__ basis, const float* __restrict__ root,
    const float* __restrict__ bias, f16* __restrict__ tcat,
    f16* __restrict__ rbuf) {
    constexpr int QP = OUT / 4;
    __shared__ float wl[3 * IN * OUT];  // W0 | W1 | root
    __shared__ float bl[OUT];
    for (int i = threadIdx.x; i < 2 * IN * OUT; i += 256) {
        const int rr = i / (IN * OUT);
        const int rem = i - rr * IN * OUT;
        float v = 0.f;
#pragma unroll
        for (int bb = 0; bb < 4; bb++)
            v = fmaf(comp[rr * 4 + bb], basis[bb * IN * OUT + rem], v);
        wl[i] = v;
    }
    for (int i = threadIdx.x; i < IN * OUT; i += 256)
        wl[2 * IN * OUT + i] = root[i];
    if (threadIdx.x < OUT) bl[threadIdx.x] = bias[threadIdx.x];
    __syncthreads();

    const int gtid = blockIdx.x * 256 + threadIdx.x;
    const int n = gtid / QP;
    const int g = gtid % QP;
    if (n >= NNODES) return;

    float4 a0 = make_float4(0.f, 0.f, 0.f, 0.f);
    float4 a1 = a0;
    float4 ar = *reinterpret_cast<const float4*>(bl + 4 * g);

    if constexpr (INH) {
        const f16* xin = (const f16*)xinp + (size_t)n * IN;
#pragma unroll
        for (int q = 0; q < IN / 8; q++) {
            const f16x8 raw = reinterpret_cast<const f16x8*>(xin)[q];
#pragma unroll
            for (int j = 0; j < 8; j++) {
                const float xv = (float)raw[j];
                const float* w0 = wl + (q * 8 + j) * OUT + 4 * g;
                fma4(a0, xv, *reinterpret_cast<const float4*>(w0));
                fma4(a1, xv, *reinterpret_cast<const float4*>(w0 + IN * OUT));
                fma4(ar, xv,
                     *reinterpret_cast<const float4*>(w0 + 2 * IN * OUT));
            }
        }
    } else {
        const float* xin = (const float*)xinp + (size_t)n * IN;
#pragma unroll
        for (int q = 0; q < IN / 4; q++) {
            const float4 xv4 = reinterpret_cast<const float4*>(xin)[q];
            const float xs[4] = {xv4.x, xv4.y, xv4.z, xv4.w};
#pragma unroll
            for (int j = 0; j < 4; j++) {
                const float* w0 = wl + (q * 4 + j) * OUT + 4 * g;
                fma4(a0, xs[j], *reinterpret_cast<const float4*>(w0));
                fma4(a1, xs[j],
                     *reinterpret_cast<const float4*>(w0 + IN * OUT));
                fma4(ar, xs[j],
                     *reinterpret_cast<const float4*>(w0 + 2 * IN * OUT));
            }
        }
    }
    f16x4 t0, t1, tr;
    t0[0] = (f16)a0.x; t0[1] = (f16)a0.y; t0[2] = (f16)a0.z; t0[3] = (f16)a0.w;
    t1[0] = (f16)a1.x; t1[1] = (f16)a1.y; t1[2] = (f16)a1.z; t1[3] = (f16)a1.w;
    tr[0] = (f16)ar.x; tr[1] = (f16)ar.y; tr[2] = (f16)ar.z; tr[3] = (f16)ar.w;
    f16* trow = tcat + (size_t)n * 2 * OUT;
    reinterpret_cast<f16x4*>(trow)[g] = t0;
    reinterpret_cast<f16x4*>(trow + OUT)[g] = t1;
    reinterpret_cast<f16x4*>(rbuf + (size_t)n * OUT)[g] = tr;
}

// ---------------- agg + root fuse: h[n] = act(mean_gather t + r[n]) --------
// 32 lanes/node: e = lane>>2 walks edges (stride 8), f = lane&3 owns OUT/4
// contiguous features. Gather = one 16B (or 8B) load per lane, coalesced.
// shfl_xor reduce over e; epilogue by e<2 (or e==0).
template <int OUT, bool RELU, bool OUTH>
__global__ __launch_bounds__(256) void aggroot_kernel(
    const f16* __restrict__ tcat, const f16* __restrict__ rbuf,
    const int* __restrict__ rowptr, const int* __restrict__ bsum,
    const int* __restrict__ cnt, const int* __restrict__ esorted,
    void* __restrict__ outp) {
    constexpr int NF = OUT / 4;  // features per f-lane
    const int gtid = blockIdx.x * 256 + threadIdx.x;
    const int n = gtid >> 5;
    if (n >= NNODES) return;
    const int lane = gtid & 31;
    const int f = lane & 3;
    const int e = lane >> 2;  // 0..7
    const int b = rowptr[n] + bsum[n >> 8];
    const int c = cnt[n];

    float a[NF];
#pragma unroll
    for (int j = 0; j < NF; j++) a[j] = 0.f;

    int i = e;
    int pk = (i < c) ? esorted[b + i] : 0;
    while (i < c) {
        const int in2 = i + 8;
        const int pkn = (in2 < c) ? esorted[b + in2] : 0;
        const int s = pk & 0x00FFFFFF;
        const int t = pk >> 24;
        const f16* row = tcat + ((size_t)s * 2 + t) * OUT + f * NF;
        if constexpr (NF == 8) {
            const f16x8 raw = *reinterpret_cast<const f16x8*>(row);
#pragma unroll
            for (int j = 0; j < 8; j++) a[j] += (float)raw[j];
        } else {
            const f16x4 raw = *reinterpret_cast<const f16x4*>(row);
#pragma unroll
            for (int j = 0; j < 4; j++) a[j] += (float)raw[j];
        }
        pk = pkn;
        i = in2;
    }
#pragma unroll
    for (int m = 4; m <= 16; m <<= 1) {
#pragma unroll
        for (int j = 0; j < NF; j++) a[j] += __shfl_xor(a[j], m);
    }
    const float inv = 1.0f / fmaxf((float)c, 1.0f);
    if constexpr (NF == 8) {
        if (e < 2) {
            const int off = f * 8 + e * 4;
            const f16x4 rv =
                *reinterpret_cast<const f16x4*>(rbuf + (size_t)n * OUT + off);
            float4 v;
            v.x = fmaf(a[e * 4 + 0], inv, (float)rv[0]);
            v.y = fmaf(a[e * 4 + 1], inv, (float)rv[1]);
            v.z = fmaf(a[e * 4 + 2], inv, (float)rv[2]);
            v.w = fmaf(a[e * 4 + 3], inv, (float)rv[3]);
            if (RELU) {
                v.x = fmaxf(v.x, 0.f);
                v.y = fmaxf(v.y, 0.f);
                v.z = fmaxf(v.z, 0.f);
                v.w = fmaxf(v.w, 0.f);
            }
            if constexpr (OUTH) {
                f16x4 hv;
                hv[0] = (f16)v.x; hv[1] = (f16)v.y;
                hv[2] = (f16)v.z; hv[3] = (f16)v.w;
                *reinterpret_cast<f16x4*>((f16*)outp + (size_t)n * OUT + off) =
                    hv;
            } else {
                *reinterpret_cast<float4*>((float*)outp + (size_t)n * OUT +
                                           off) = v;
            }
        }
    } else {
        if (e == 0) {
            const int off = f * 4;
            const f16x4 rv =
                *reinterpret_cast<const f16x4*>(rbuf + (size_t)n * OUT + off);
            float4 v;
            v.x = fmaf(a[0], inv, (float)rv[0]);
            v.y = fmaf(a[1], inv, (float)rv[1]);
            v.z = fmaf(a[2], inv, (float)rv[2]);
            v.w = fmaf(a[3], inv, (float)rv[3]);
            if (RELU) {
                v.x = fmaxf(v.x, 0.f);
                v.y = fmaxf(v.y, 0.f);
                v.z = fmaxf(v.z, 0.f);
                v.w = fmaxf(v.w, 0.f);
            }
            if constexpr (OUTH) {
                f16x4 hv;
                hv[0] = (f16)v.x; hv[1] = (f16)v.y;
                hv[2] = (f16)v.z; hv[3] = (f16)v.w;
                *reinterpret_cast<f16x4*>((f16*)outp + (size_t)n * OUT + off) =
                    hv;
            } else {
                *reinterpret_cast<float4*>((float*)outp + (size_t)n * OUT +
                                           off) = v;
            }
        }
    }
}

// ---------------- decode precompute: u[n][t] = z[n] @ Wd_t + bd_t (fp16) ----
// 2 threads per node (one per relation); W staged in LDS.
__global__ __launch_bounds__(256) void uproj_kernel(
    const f16* __restrict__ zh, const float* __restrict__ wp,
    const float* __restrict__ bp, const float* __restrict__ wm,
    const float* __restrict__ bm, f16* __restrict__ u) {
    __shared__ float wl[2 * 256];
    __shared__ float bl[2 * 16];
    {
        const int i = threadIdx.x;
        wl[i] = wp[i];
        wl[256 + i] = wm[i];
        if (i < 16) {
            bl[i] = bp[i];
            bl[16 + i] = bm[i];
        }
    }
    __syncthreads();
    const int gtid = blockIdx.x * 256 + threadIdx.x;
    const int n = gtid >> 1;
    const int t = gtid & 1;
    if (n >= NNODES) return;
    const f16x8 z0 = reinterpret_cast<const f16x8*>(zh + (size_t)n * 16)[0];
    const f16x8 z1 = reinterpret_cast<const f16x8*>(zh + (size_t)n * 16)[1];
    float acc[16];
#pragma unroll
    for (int j = 0; j < 16; j++) acc[j] = bl[t * 16 + j];
    const float* W = wl + t * 256;
#pragma unroll
    for (int k = 0; k < 8; k++) {
        const float zk = (float)z0[k];
#pragma unroll
        for (int j = 0; j < 16; j++) acc[j] = fmaf(zk, W[k * 16 + j], acc[j]);
    }
#pragma unroll
    for (int k = 0; k < 8; k++) {
        const float zk = (float)z1[k];
#pragma unroll
        for (int j = 0; j < 16; j++)
            acc[j] = fmaf(zk, W[(8 + k) * 16 + j], acc[j]);
    }
    f16x8 o0, o1;
#pragma unroll
    for (int j = 0; j < 8; j++) {
        o0[j] = (f16)acc[j];
        o1[j] = (f16)acc[8 + j];
    }
    f16* ur = u + (size_t)n * 32 + t * 16;
    reinterpret_cast<f16x8*>(ur)[0] = o0;
    reinterpret_cast<f16x8*>(ur)[1] = o1;
}

// ---------------- decode: score = u[s,t] . z[d], 2 lanes per edge ----------
__global__ __launch_bounds__(256) void decode_kernel(
    const f16* __restrict__ u, const f16* __restrict__ zh,
    const int* __restrict__ pei, const int* __restrict__ pet,
    const int* __restrict__ nei, const int* __restrict__ net,
    float* __restrict__ out) {
    const int gtid = blockIdx.x * 256 + threadIdx.x;
    const int e = gtid >> 1;
    const int h = gtid & 1;
    if (e >= EPOS + ENEG) return;
    int s, d, t;
    if (e < EPOS) {
        s = pei[e];
        d = pei[e + EPOS];
        t = pet[e];
    } else {
        const int ee = e - EPOS;
        s = nei[ee];
        d = nei[ee + ENEG];
        t = net[ee];
    }
    const f16x8 uv =
        *reinterpret_cast<const f16x8*>(u + (size_t)s * 32 + t * 16 + h * 8);
    const f16x8 zv =
        *reinterpret_cast<const f16x8*>(zh + (size_t)d * 16 + h * 8);
    float sc = 0.f;
#pragma unroll
    for (int j = 0; j < 8; j++) sc = fmaf((float)uv[j], (float)zv[j], sc);
    sc += __shfl_xor(sc, 1);
    if (h == 0) out[e] = sc;
}

extern "C" void kernel_launch(void* const* d_in, const int* in_sizes, int n_in,
                              void* d_out, int out_size, void* d_ws,
                              size_t ws_size, hipStream_t stream) {
    const float* x_paper = (const float*)d_in[0];
    const float* x_mesh = (const float*)d_in[1];
    const float* tp_w = (const float*)d_in[2];
    const float* tp_b = (const float*)d_in[3];
    const float* tm_w = (const float*)d_in[4];
    const float* tm_b = (const float*)d_in[5];
    const float* comp1 = (const float*)d_in[6];
    const float* basis1 = (const float*)d_in[7];
    const float* root1 = (const float*)d_in[8];
    const float* bias1 = (const float*)d_in[9];
    const float* comp2 = (const float*)d_in[10];
    const float* basis2 = (const float*)d_in[11];
    const float* root2 = (const float*)d_in[12];
    const float* bias2 = (const float*)d_in[13];
    const float* comp3 = (const float*)d_in[14];
    const float* basis3 = (const float*)d_in[15];
    const float* root3 = (const float*)d_in[16];
    const float* bias3 = (const float*)d_in[17];
    const float* dpp_w = (const float*)d_in[18];
    const float* dpp_b = (const float*)d_in[19];
    const float* dpm_w = (const float*)d_in[20];
    const float* dpm_b = (const float*)d_in[21];
    const int* tei = (const int*)d_in[22];
    const int* tet = (const int*)d_in[23];
    const int* pei = (const int*)d_in[24];
    const int* pet = (const int*)d_in[25];
    const int* nei = (const int*)d_in[26];
    const int* net = (const int*)d_in[27];
    float* out = (float*)d_out;

    // workspace layout (in float units), no live-range overlap:
    const size_t N = NNODES;
    float* ws = (float*)d_ws;
    float* xfeat = ws;                       // 16N fp32
    f16* rbuf = (f16*)(ws + 16 * N);         // 32 f16/node = 16N fl-equiv
    f16* tcat = (f16*)(ws + 32 * N);         // 64 f16/node = 32N fl-equiv
    f16* h1 = (f16*)(ws + 64 * N);           // 32 f16/node = 16N
    f16* h2 = (f16*)(ws + 80 * N);           // 16N
    f16* zh = (f16*)(ws + 96 * N);           // 16 f16/node = 8N
    f16* u = (f16*)(ws + 104 * N);           // 32 f16/node = 16N
    int* rowptr = (int*)(ws + 120 * N);      // N
    int* ecnt = rowptr + N;                  // N
    int* fc = ecnt + N;                      // N (adjacent: one memset)
    int* esorted = fc + N;                   // E_TRAIN
    int* bsum = esorted + ETRAIN;            // ~900

    const int* tsrc = tei;
    const int* tdst = tei + ETRAIN;

    const int eblocks = (ETRAIN + 255) / 256;
    const int nb = (NNODES + 255) / 256;             // 899
    const int aggb = (NNODES * 32 + 255) / 256;      // 28750

    // ---- encode ----
    encode_kernel<512><<<(NPAPER + 255) / 256, 256, 0, stream>>>(
        x_paper, tp_w, tp_b, xfeat, NPAPER);
    encode_kernel<128><<<(NMESH + 255) / 256, 256, 0, stream>>>(
        x_mesh, tm_w, tm_b, xfeat + (size_t)NPAPER * 16, NMESH);

    // ---- CSR build (once; reused by all 3 layers) ----
    hipMemsetAsync(ecnt, 0, (size_t)2 * NNODES * 4, stream);  // ecnt + fc
    hist_kernel<<<eblocks, 256, 0, stream>>>(tdst, ecnt);
    scan1_kernel<<<nb, 256, 0, stream>>>(ecnt, rowptr, bsum, NNODES);
    scan2_kernel<<<1, 256, 0, stream>>>(bsum, nb);
    fill_kernel<<<eblocks, 256, 0, stream>>>(tsrc, tdst, tet, rowptr, bsum,
                                             fc, esorted);

    // ---- layer 1: 16 -> 32, relu ----
    transform_kernel<16, 32, false>
        <<<(NNODES * 8 + 255) / 256, 256, 0, stream>>>(xfeat, comp1, basis1,
                                                       root1, bias1, tcat,
                                                       rbuf);
    aggroot_kernel<32, true, true><<<aggb, 256, 0, stream>>>(
        tcat, rbuf, rowptr, bsum, ecnt, esorted, h1);

    // ---- layer 2: 32 -> 32, relu ----
    transform_kernel<32, 32, true>
        <<<(NNODES * 8 + 255) / 256, 256, 0, stream>>>(h1, comp2, basis2,
                                                       root2, bias2, tcat,
                                                       rbuf);
    aggroot_kernel<32, true, true><<<aggb, 256, 0, stream>>>(
        tcat, rbuf, rowptr, bsum, ecnt, esorted, h2);

    // ---- layer 3: 32 -> 16, no relu, fp16 z out ----
    transform_kernel<32, 16, true>
        <<<(NNODES * 4 + 255) / 256, 256, 0, stream>>>(h2, comp3, basis3,
                                                       root3, bias3, tcat,
                                                       rbuf);
    aggroot_kernel<16, false, true><<<aggb, 256, 0, stream>>>(
        tcat, rbuf, rowptr, bsum, ecnt, esorted, zh);

    // ---- decode: per-node projection, then gather-dot (2 lanes/edge) ----
    uproj_kernel<<<(NNODES * 2 + 255) / 256, 256, 0, stream>>>(
        zh, dpp_w, dpp_b, dpm_w, dpm_b, u);
    decode_kernel<<<((EPOS + ENEG) * 2 + 255) / 256, 256, 0, stream>>>(
        u, zh, pei, pet, nei, net, out);
}